// Round 4
// baseline (71.672 us; speedup 1.0000x reference)
//
#include <hip/hip_runtime.h>

#define NBINS 256
#define BATCH 32
#define HW (512 * 512)
#define NSUB 4  // per-wave sub-histograms (256 threads = 4 waves)

__global__ __launch_bounds__(256) void hist_kernel(
    const float* __restrict__ img,    // [B,3,H,W]
    const float* __restrict__ depth,  // [B,1,H,W]
    float* __restrict__ sums,         // [B,NBINS]
    unsigned int* __restrict__ cnts,  // [B,NBINS]
    int blocksPerSample)
{
    __shared__ float s_sum[NSUB][NBINS];
    __shared__ unsigned int s_cnt[NSUB][NBINS];

    const int tid  = threadIdx.x;
    const int wave = tid >> 6;

    // zero LDS histograms
    for (int i = tid; i < NSUB * NBINS; i += 256) {
        ((float*)s_sum)[i] = 0.0f;
        ((unsigned int*)s_cnt)[i] = 0u;
    }
    __syncthreads();

    const int b     = blockIdx.x / blocksPerSample;
    const int chunk = blockIdx.x % blocksPerSample;
    const int pixPerBlock = HW / blocksPerSample;  // 4096
    const int base = chunk * pixPerBlock;

    const float4* Rp = (const float4*)(img + (size_t)b * 3 * HW + 0 * HW + base);
    const float4* Gp = (const float4*)(img + (size_t)b * 3 * HW + 1 * HW + base);
    const float4* Bp = (const float4*)(img + (size_t)b * 3 * HW + 2 * HW + base);
    const float4* Dp = (const float4*)(depth + (size_t)b * HW + base);

    const int nvec = pixPerBlock / 4;  // 1024 float4s
    for (int i = tid; i < nvec; i += 256) {
        float4 r = Rp[i];
        float4 g = Gp[i];
        float4 bl = Bp[i];
        float4 d = Dp[i];

        float il0 = 0.2f * r.x + 0.7f * g.x + 0.1f * bl.x;
        float il1 = 0.2f * r.y + 0.7f * g.y + 0.1f * bl.y;
        float il2 = 0.2f * r.z + 0.7f * g.z + 0.1f * bl.z;
        float il3 = 0.2f * r.w + 0.7f * g.w + 0.1f * bl.w;

        int k0 = (int)(d.x * 255.0f + 0.5f);
        int k1 = (int)(d.y * 255.0f + 0.5f);
        int k2 = (int)(d.z * 255.0f + 0.5f);
        int k3 = (int)(d.w * 255.0f + 0.5f);
        k0 = min(max(k0, 0), NBINS - 1);
        k1 = min(max(k1, 0), NBINS - 1);
        k2 = min(max(k2, 0), NBINS - 1);
        k3 = min(max(k3, 0), NBINS - 1);

        atomicAdd(&s_sum[wave][k0], il0);
        atomicAdd(&s_cnt[wave][k0], 1u);
        atomicAdd(&s_sum[wave][k1], il1);
        atomicAdd(&s_cnt[wave][k1], 1u);
        atomicAdd(&s_sum[wave][k2], il2);
        atomicAdd(&s_cnt[wave][k2], 1u);
        atomicAdd(&s_sum[wave][k3], il3);
        atomicAdd(&s_cnt[wave][k3], 1u);
    }
    __syncthreads();

    // fold sub-histograms, one global atomic per bin per block
    for (int k = tid; k < NBINS; k += 256) {
        float s = s_sum[0][k] + s_sum[1][k] + s_sum[2][k] + s_sum[3][k];
        unsigned int c = s_cnt[0][k] + s_cnt[1][k] + s_cnt[2][k] + s_cnt[3][k];
        atomicAdd(&sums[b * NBINS + k], s);
        atomicAdd(&cnts[b * NBINS + k], c);
    }
}

__global__ __launch_bounds__(256) void finalize_kernel(
    const float* __restrict__ sums,
    const unsigned int* __restrict__ cnts,
    float* __restrict__ out)
{
    __shared__ float mean[NBINS];
    __shared__ float wsum[4];

    const int k = threadIdx.x;
    float acc = 0.0f;

    for (int b = 0; b < BATCH; ++b) {
        float m = sums[b * NBINS + k] / (float)cnts[b * NBINS + k];
        mean[k] = m;
        __syncthreads();
        if (k < NBINS - 1) {
            float d = mean[k] - mean[k + 1];
            acc += fmaxf(d, 0.0f);
        }
        __syncthreads();
    }

    // wave64 reduce
    for (int off = 32; off > 0; off >>= 1)
        acc += __shfl_down(acc, off, 64);
    if ((k & 63) == 0) wsum[k >> 6] = acc;
    __syncthreads();
    if (k == 0) {
        float total = wsum[0] + wsum[1] + wsum[2] + wsum[3];
        out[0] = total / (255.0f * (float)BATCH);
    }
}

extern "C" void kernel_launch(void* const* d_in, const int* in_sizes, int n_in,
                              void* d_out, int out_size, void* d_ws, size_t ws_size,
                              hipStream_t stream)
{
    const float* img   = (const float*)d_in[0];
    const float* depth = (const float*)d_in[1];
    float* out = (float*)d_out;

    float* sums        = (float*)d_ws;
    unsigned int* cnts = (unsigned int*)((char*)d_ws + (size_t)BATCH * NBINS * sizeof(float));

    // zero the accumulators every call (harness does not re-poison between replays)
    hipMemsetAsync(d_ws, 0, (size_t)BATCH * NBINS * (sizeof(float) + sizeof(unsigned int)), stream);

    const int blocksPerSample = 64;
    hist_kernel<<<BATCH * blocksPerSample, 256, 0, stream>>>(img, depth, sums, cnts, blocksPerSample);
    finalize_kernel<<<1, 256, 0, stream>>>(sums, cnts, out);
}

// Round 5
// 35.028 us; speedup vs baseline: 2.0462x; 2.0462x over previous
//
#include <hip/hip_runtime.h>

#define NBINS 256
#define BATCH 32
#define HW (512 * 512)
#define NSUB 4  // per-wave sub-histograms (256 threads = 4 waves)

// Packed fixed-point histogram cell:
//   bits [0:43]  : sum of illum * 2^24  (per-global-bin max 2^42)
//   bits [44:63] : count               (per-global-bin max 2^18)
#define CNT_SHIFT 44
#define SUM_MASK ((1ull << CNT_SHIFT) - 1)
#define FIX_SCALE 16777216.0f  // 2^24

__global__ __launch_bounds__(256) void hist_kernel(
    const float* __restrict__ img,    // [B,3,H,W]
    const float* __restrict__ depth,  // [B,1,H,W]
    unsigned long long* __restrict__ hist,  // [B,NBINS] packed
    int blocksPerSample)
{
    __shared__ unsigned long long s_hist[NSUB][NBINS];

    const int tid  = threadIdx.x;
    const int wave = tid >> 6;

    // zero LDS histograms (4*256 u64 = 8 KB)
    for (int i = tid; i < NSUB * NBINS; i += 256)
        ((unsigned long long*)s_hist)[i] = 0ull;
    __syncthreads();

    const int b     = blockIdx.x / blocksPerSample;
    const int chunk = blockIdx.x % blocksPerSample;
    const int pixPerBlock = HW / blocksPerSample;  // 4096
    const int base = chunk * pixPerBlock;

    const float4* Rp = (const float4*)(img + (size_t)b * 3 * HW + 0 * HW + base);
    const float4* Gp = (const float4*)(img + (size_t)b * 3 * HW + 1 * HW + base);
    const float4* Bp = (const float4*)(img + (size_t)b * 3 * HW + 2 * HW + base);
    const float4* Dp = (const float4*)(depth + (size_t)b * HW + base);

    const int nvec = pixPerBlock / 4;  // 1024 float4s per block
    for (int i = tid; i < nvec; i += 256) {
        float4 r  = Rp[i];
        float4 g  = Gp[i];
        float4 bl = Bp[i];
        float4 d  = Dp[i];

        float il0 = 0.2f * r.x + 0.7f * g.x + 0.1f * bl.x;
        float il1 = 0.2f * r.y + 0.7f * g.y + 0.1f * bl.y;
        float il2 = 0.2f * r.z + 0.7f * g.z + 0.1f * bl.z;
        float il3 = 0.2f * r.w + 0.7f * g.w + 0.1f * bl.w;

        int k0 = (int)(d.x * 255.0f + 0.5f);
        int k1 = (int)(d.y * 255.0f + 0.5f);
        int k2 = (int)(d.z * 255.0f + 0.5f);
        int k3 = (int)(d.w * 255.0f + 0.5f);
        k0 = min(max(k0, 0), NBINS - 1);
        k1 = min(max(k1, 0), NBINS - 1);
        k2 = min(max(k2, 0), NBINS - 1);
        k3 = min(max(k3, 0), NBINS - 1);

        // one native ds_add_u64 per pixel (count packed in high bits)
        unsigned long long v0 = (1ull << CNT_SHIFT) | (unsigned long long)(unsigned int)(il0 * FIX_SCALE + 0.5f);
        unsigned long long v1 = (1ull << CNT_SHIFT) | (unsigned long long)(unsigned int)(il1 * FIX_SCALE + 0.5f);
        unsigned long long v2 = (1ull << CNT_SHIFT) | (unsigned long long)(unsigned int)(il2 * FIX_SCALE + 0.5f);
        unsigned long long v3 = (1ull << CNT_SHIFT) | (unsigned long long)(unsigned int)(il3 * FIX_SCALE + 0.5f);

        atomicAdd(&s_hist[wave][k0], v0);
        atomicAdd(&s_hist[wave][k1], v1);
        atomicAdd(&s_hist[wave][k2], v2);
        atomicAdd(&s_hist[wave][k3], v3);
    }
    __syncthreads();

    // fold sub-histograms, one global packed atomic per bin per block
    for (int k = tid; k < NBINS; k += 256) {
        unsigned long long v = s_hist[0][k] + s_hist[1][k] + s_hist[2][k] + s_hist[3][k];
        atomicAdd(&hist[b * NBINS + k], v);
    }
}

__global__ __launch_bounds__(1024) void finalize_kernel(
    const unsigned long long* __restrict__ hist,  // [B,NBINS] packed
    float* __restrict__ out)
{
    __shared__ float mean[BATCH * NBINS];  // 32 KB
    __shared__ float wsum[16];

    const int tid = threadIdx.x;

    // compute all 8192 means in one pass
    for (int p = tid; p < BATCH * NBINS; p += 1024) {
        unsigned long long v = hist[p];
        float s = (float)(v & SUM_MASK) * (1.0f / FIX_SCALE);
        float c = (float)(unsigned int)(v >> CNT_SHIFT);
        mean[p] = s / c;
    }
    __syncthreads();

    float acc = 0.0f;
    for (int p = tid; p < BATCH * NBINS; p += 1024) {
        int k = p & (NBINS - 1);
        if (k < NBINS - 1) {
            float d = mean[p] - mean[p + 1];
            acc += fmaxf(d, 0.0f);
        }
    }

    // wave64 reduce, then cross-wave
    for (int off = 32; off > 0; off >>= 1)
        acc += __shfl_down(acc, off, 64);
    if ((tid & 63) == 0) wsum[tid >> 6] = acc;
    __syncthreads();
    if (tid == 0) {
        float total = 0.0f;
        for (int w = 0; w < 16; ++w) total += wsum[w];
        out[0] = total / (255.0f * (float)BATCH);
    }
}

extern "C" void kernel_launch(void* const* d_in, const int* in_sizes, int n_in,
                              void* d_out, int out_size, void* d_ws, size_t ws_size,
                              hipStream_t stream)
{
    const float* img   = (const float*)d_in[0];
    const float* depth = (const float*)d_in[1];
    float* out = (float*)d_out;

    unsigned long long* hist = (unsigned long long*)d_ws;

    // zero accumulators every call (deterministic under graph replay)
    hipMemsetAsync(d_ws, 0, (size_t)BATCH * NBINS * sizeof(unsigned long long), stream);

    const int blocksPerSample = 64;
    hist_kernel<<<BATCH * blocksPerSample, 256, 0, stream>>>(img, depth, hist, blocksPerSample);
    finalize_kernel<<<1, 1024, 0, stream>>>(hist, out);
}